// Round 10
// baseline (580.367 us; speedup 1.0000x reference)
//
#include <hip/hip_runtime.h>
#include <hip/hip_fp16.h>

// GAT (3-layer) on MI355X. N=50000 nodes, E=800000 edges, D=64, H=2/2/1.
// R16 = R15 + degree-sorted node permutation for k_agg_gp (one variable).
//      Diagnosis: group-per-node block lives until its slowest of 16 groups;
//      deg ~ Poisson(16) -> max-of-16 ~ 27 vs mean 16 = ~1.7x residency waste
//      (occ 51% with VALU 37% + HBM 40% both unsaturated = allocated-idle).
//      Counting sort by degree (counts[n] = degree after k_hist_rank; 1024
//      bins): k_deg_hist -> k_deg_scan (1 block) -> k_deg_scatter builds perm;
//      agg maps group -> perm[blockIdx*16+gq] so blocks have uniform degree.

typedef __attribute__((ext_vector_type(8))) short short8;   // 8 bf16 (4 VGPRs)
typedef __attribute__((ext_vector_type(4))) float float4v;  // 4 fp32 acc

__device__ __forceinline__ float lrelu(float x){ return fmaxf(x, 0.2f*x); }

__device__ __forceinline__ unsigned short f2bf(float f){   // RNE round
  unsigned int u = __float_as_uint(f);
  u += 0x7fffu + ((u >> 16) & 1u);
  return (unsigned short)(u >> 16);
}
__device__ __forceinline__ unsigned short f2h(float f){
  return __half_as_ushort(__float2half(f));
}
__device__ __forceinline__ float elu1(float x){            // elu, x<0 branch via exp
  return x > 0.f ? x : (__expf(x) - 1.f);
}

// hist + rank in one atomic: rank[i] = position of edge i within its dst bucket
__global__ void k_hist_rank(const int* __restrict__ dst, int* __restrict__ counts,
                            int* __restrict__ rank, int E){
  int i = blockIdx.x*blockDim.x + threadIdx.x;
  if (i < E){
    int d = dst[i];
    rank[i] = atomicAdd(&counts[d], 1);
  }
}

__global__ void k_scan_local(const int* __restrict__ counts, int* __restrict__ row_ptr,
                             int* __restrict__ bsum, int N){
  __shared__ int s[256];
  int t = threadIdx.x, g = blockIdx.x*256 + t;
  int v = (g < N) ? counts[g] : 0;
  s[t] = v; __syncthreads();
  #pragma unroll
  for (int off = 1; off < 256; off <<= 1){
    int x = 0;
    if (t >= off) x = s[t-off];
    __syncthreads();
    s[t] += x;
    __syncthreads();
  }
  if (g < N) row_ptr[g+1] = s[t];
  if (g == 0 && t == 0) row_ptr[0] = 0;
  if (t == 255) bsum[blockIdx.x] = s[255];
}

__global__ void k_scan_top(int* __restrict__ bsum, int nb){
  __shared__ int s[256];
  int t = threadIdx.x;
  int v = (t < nb) ? bsum[t] : 0;
  s[t] = v; __syncthreads();
  #pragma unroll
  for (int off = 1; off < 256; off <<= 1){
    int x = 0;
    if (t >= off) x = s[t-off];
    __syncthreads();
    s[t] += x;
    __syncthreads();
  }
  if (t < nb) bsum[t] = s[t] - v;  // exclusive block offsets
}

__global__ void k_scan_fix(int* __restrict__ row_ptr, const int* __restrict__ bsum, int N){
  int g = blockIdx.x*256 + threadIdx.x;
  if (g < N && blockIdx.x > 0) row_ptr[g+1] += bsum[blockIdx.x];
}

// atomic-free scatter: pos comes from rank captured during hist
__global__ void k_scatter2(const int* __restrict__ src, const int* __restrict__ dst,
                           const int* __restrict__ rank, const int* __restrict__ row_ptr,
                           int* __restrict__ ssrc, int E){
  int i = blockIdx.x*blockDim.x + threadIdx.x;
  if (i < E) ssrc[row_ptr[dst[i]] + rank[i]] = src[i];
}

// ---- degree counting sort (counts[n] = degree after k_hist_rank) ----
__global__ void k_deg_hist(const int* __restrict__ counts, int* __restrict__ dcnt, int N){
  int n = blockIdx.x*256 + threadIdx.x;
  if (n < N) atomicAdd(&dcnt[min(counts[n], 1023)], 1);
}

// exclusive scan of 1024 bins in one 256-thread block (4 bins/thread)
__global__ void k_deg_scan(const int* __restrict__ dcnt, int* __restrict__ doff){
  __shared__ int s[256];
  int t = threadIdx.x;
  int v[4]; int sum = 0;
  #pragma unroll
  for (int q = 0; q < 4; q++){ v[q] = dcnt[t*4+q]; sum += v[q]; }
  s[t] = sum; __syncthreads();
  #pragma unroll
  for (int off = 1; off < 256; off <<= 1){
    int x = 0;
    if (t >= off) x = s[t-off];
    __syncthreads();
    s[t] += x;
    __syncthreads();
  }
  int base = (t == 0) ? 0 : s[t-1];
  #pragma unroll
  for (int q = 0; q < 4; q++){ doff[t*4+q] = base; base += v[q]; }
}

__global__ void k_deg_scatter(const int* __restrict__ counts, int* __restrict__ doff,
                              int* __restrict__ perm, int N){
  int n = blockIdx.x*256 + threadIdx.x;
  if (n < N){
    int pos = atomicAdd(&doff[min(counts[n], 1023)], 1);
    perm[pos] = n;
  }
}

// Fused setup: zero counts + degree bins + all three weight preps.
// Wt layout: [n][IN] bf16 (n-major). W0: 64x128; W1: 128x128; W2|rW2: 128x(64+64).
__global__ void k_setup(int* __restrict__ counts, int* __restrict__ dcnt, int N,
                        const float* __restrict__ W0, const float* __restrict__ W1,
                        const float* __restrict__ W2, const float* __restrict__ rW2,
                        unsigned short* __restrict__ Wt0, unsigned short* __restrict__ Wt1,
                        unsigned short* __restrict__ Wt2){
  int id = blockIdx.x*256 + threadIdx.x;
  if (id < N){ counts[id] = 0; return; }
  int j = id - N;
  if (j < 1024){ dcnt[j] = 0; return; }
  j -= 1024;
  if (j < 128*64){
    int n = j/64, k = j%64;
    Wt0[n*64 + k] = f2bf(W0[k*128 + n]);
  } else if (j < 128*64 + 128*128){
    int i = j - 128*64; int n = i/128, k = i%128;
    Wt1[n*128 + k] = f2bf(W1[k*128 + n]);
  } else if (j < 128*64 + 2*128*128){
    int i = j - 128*64 - 128*128; int n = i/128, k = i%128;
    float v = (n < 64) ? W2[k*64 + n] : rW2[k*64 + (n - 64)];
    Wt2[n*128 + k] = f2bf(v);
  }
}

// MFMA GEMM: fhb[N][128](f16 row-major) = A[N][IN] @ W(128 cols via Wt).
// A source: hb bf16 (EMBED=false) or emb[feat[n]]*fv[n] converted on the fly
// (EMBED=true, IN==64). Block 256 thr = 4 waves; wave: 16 rows x 128 cols.
// Layouts (verified): A[m=lane&15][k=quad*8+j]; B[k=quad*8+j][n=lane&15];
// D: col=lane&15, row=quad*4+reg. el/er fused (16-lane butterfly per quad).
template<int IN, int H, bool EMBED>
__global__ __launch_bounds__(256) void k_gemm_mfma(
    const unsigned short* __restrict__ hb,   // [N][IN] bf16 (unused if EMBED)
    const int* __restrict__ feat, const float* __restrict__ fv,
    const float* __restrict__ embp,          // [VOCAB][64] f32
    const unsigned short* __restrict__ Wt,   // [128][IN] bf16, n-major
    const float* __restrict__ al, const float* __restrict__ ar,
    unsigned short* __restrict__ fhb,        // [N][128] f16
    float* __restrict__ elr, int N){
  constexpr int KS = IN/32;
  constexpr int LDP = IN + 8;                // +8 bf16 pad: 2-way banks only
  __shared__ unsigned short Wt_s[128*LDP];
  const int t = threadIdx.x;
  const int lane = t & 63, wid = t >> 6;
  const int l15 = lane & 15, quad = lane >> 4;
  const int row0 = blockIdx.x*64 + wid*16;

  // stage Wt -> LDS (uint4 = 8 bf16)
  for (int id = t; id < 128*(IN/8); id += 256){
    int r = id/(IN/8), seg = id%(IN/8);
    ((uint4*)(Wt_s + r*LDP))[seg] = ((const uint4*)(Wt + (size_t)r*IN))[seg];
  }
  // A fragments from global (overlaps LDS staging)
  short8 a[KS];
  int arow = row0 + l15;
  if (EMBED){
    if (arow < N){
      const float* er2 = embp + (size_t)feat[arow]*64;
      float sc = fv[arow];
      #pragma unroll
      for (int s = 0; s < KS; s++){
        const float4* p = (const float4*)(er2 + s*32 + quad*8);
        float4 v0 = p[0], v1 = p[1];
        short8 ta;
        ta[0] = (short)f2bf(v0.x*sc); ta[1] = (short)f2bf(v0.y*sc);
        ta[2] = (short)f2bf(v0.z*sc); ta[3] = (short)f2bf(v0.w*sc);
        ta[4] = (short)f2bf(v1.x*sc); ta[5] = (short)f2bf(v1.y*sc);
        ta[6] = (short)f2bf(v1.z*sc); ta[7] = (short)f2bf(v1.w*sc);
        a[s] = ta;
      }
    } else {
      #pragma unroll
      for (int s = 0; s < KS; s++) a[s] = short8{0,0,0,0,0,0,0,0};
    }
  } else {
    #pragma unroll
    for (int s = 0; s < KS; s++){
      if (arow < N) a[s] = *(const short8*)(hb + (size_t)arow*IN + s*32 + quad*8);
      else          a[s] = short8{0,0,0,0,0,0,0,0};
    }
  }
  __syncthreads();

  float4v acc[8];
  #pragma unroll
  for (int nt = 0; nt < 8; nt++) acc[nt] = float4v{0.f,0.f,0.f,0.f};
  #pragma unroll
  for (int nt = 0; nt < 8; nt++){
    #pragma unroll
    for (int s = 0; s < KS; s++){
      short8 b = *(const short8*)(Wt_s + (nt*16 + l15)*LDP + s*32 + quad*8);
      acc[nt] = __builtin_amdgcn_mfma_f32_16x16x32_bf16(a[s], b, acc[nt], 0, 0, 0);
    }
  }

  // al/ar at this lane's columns (col = nt*16 + l15); H==1: heads>0 are zero
  float alc[8], arc[8];
  #pragma unroll
  for (int nt = 0; nt < 8; nt++){
    bool hv = (H == 2) || (nt < 4);
    alc[nt] = hv ? al[nt*16 + l15] : 0.f;
    arc[nt] = hv ? ar[nt*16 + l15] : 0.f;
  }
  #pragma unroll
  for (int reg = 0; reg < 4; reg++){
    int row = row0 + quad*4 + reg;
    bool rv = row < N;
    if (rv){
      #pragma unroll
      for (int nt = 0; nt < 8; nt++)
        fhb[(size_t)row*128 + nt*16 + l15] = f2h(acc[nt][reg]);
    }
    float pel0 = 0.f, per0 = 0.f, pel1 = 0.f, per1 = 0.f;
    #pragma unroll
    for (int nt = 0; nt < 4; nt++){
      pel0 += acc[nt][reg]*alc[nt];     per0 += acc[nt][reg]*arc[nt];
      pel1 += acc[nt+4][reg]*alc[nt+4]; per1 += acc[nt+4][reg]*arc[nt+4];
    }
    #pragma unroll
    for (int off = 1; off < 16; off <<= 1){   // reduce across the 16 lanes of a quad
      pel0 += __shfl_xor(pel0, off, 64);
      pel1 += __shfl_xor(pel1, off, 64);
      per0 += __shfl_xor(per0, off, 64);
      per1 += __shfl_xor(per1, off, 64);
    }
    if (l15 == 0 && rv){
      elr[row*4+0] = pel0;
      elr[row*4+1] = (H == 2) ? pel1 : 0.f;
      elr[row*4+2] = per0;
      elr[row*4+3] = (H == 2) ? per1 : 0.f;
    }
  }
}

// GROUP-PER-NODE aggregation: block = 256 thr = 16 groups of 16 lanes; each
// group owns ONE node (via degree-sorted perm -> uniform trip counts within
// a block) and streams its edges. Lane c holds a 16B (H=2, full 256B row) /
// 8B (H=1, cols 0..63) chunk. alpha computed inline per edge (same value in
// all 16 lanes — no cross-lane ops anywhere). den accumulates identically per
// lane -> epilogue reciprocal needs no reduce. 4-deep main loop: 4 independent
// ssrc->elr->row chains, 12 VMEM in flight.
template<int H>
__global__ __launch_bounds__(256) void k_agg_gp(
    const unsigned short* __restrict__ fhb,  // [N][128] f16
    const float* __restrict__ elr,           // [N][4]
    const int* __restrict__ row_ptr, const int* __restrict__ ssrc,
    const int* __restrict__ perm,            // degree-sorted node ids
    const float* __restrict__ bias, const float* __restrict__ res,
    int act, int res_from_fh,
    float* __restrict__ out, int out_ld, unsigned* __restrict__ outb, int N){
  const int t = threadIdx.x;
  const int gq = t >> 4, c = t & 15;         // group, lane-in-group
  const int idx = blockIdx.x*16 + gq;
  if (idx >= N) return;
  const int n = perm[idx];
  const int beg = row_ptr[n], end = row_ptr[n+1];
  const float er0 = elr[n*4+2];
  const float er1 = (H == 2) ? elr[n*4+3] : 0.f;

  const char* fhbB = (const char*)fhb;       // row = 256 B, 32-bit offsets
  const unsigned cb = (H == 2) ? ((unsigned)c << 4) : ((unsigned)c << 3);
  constexpr int PC = (H == 2) ? 8 : 4;       // cols per lane

  float acc[PC];
  #pragma unroll
  for (int k = 0; k < PC; k++) acc[k] = 0.f;
  float den0 = 0.f, den1 = 0.f;

  int i = beg;
  for (; i + 3 < end; i += 4){               // 4-deep: 4 independent chains
    int s0 = ssrc[i],   s1 = ssrc[i+1];
    int s2 = ssrc[i+2], s3 = ssrc[i+3];
    float2 el0 = *(const float2*)(elr + s0*4);
    float2 el1 = *(const float2*)(elr + s1*4);
    float2 el2 = *(const float2*)(elr + s2*4);
    float2 el3 = *(const float2*)(elr + s3*4);
    if (H == 2){
      uint4 w0 = *(const uint4*)(fhbB + (((unsigned)s0 << 8) + cb));
      uint4 w1 = *(const uint4*)(fhbB + (((unsigned)s1 << 8) + cb));
      uint4 w2 = *(const uint4*)(fhbB + (((unsigned)s2 << 8) + cb));
      uint4 w3 = *(const uint4*)(fhbB + (((unsigned)s3 << 8) + cb));
      float e00 = __expf(fminf(lrelu(el0.x + er0), 30.f));
      float e10 = __expf(fminf(lrelu(el1.x + er0), 30.f));
      float e20 = __expf(fminf(lrelu(el2.x + er0), 30.f));
      float e30 = __expf(fminf(lrelu(el3.x + er0), 30.f));
      float e01 = __expf(fminf(lrelu(el0.y + er1), 30.f));
      float e11 = __expf(fminf(lrelu(el1.y + er1), 30.f));
      float e21 = __expf(fminf(lrelu(el2.y + er1), 30.f));
      float e31 = __expf(fminf(lrelu(el3.y + er1), 30.f));
      den0 += (e00 + e10) + (e20 + e30);
      den1 += (e01 + e11) + (e21 + e31);
      float a0 = (c < 8) ? e00 : e01;        // head = col/64
      float a1 = (c < 8) ? e10 : e11;
      float a2 = (c < 8) ? e20 : e21;
      float a3 = (c < 8) ? e30 : e31;
      const __half2* h0 = (const __half2*)&w0;
      const __half2* h1 = (const __half2*)&w1;
      const __half2* h2 = (const __half2*)&w2;
      const __half2* h3 = (const __half2*)&w3;
      #pragma unroll
      for (int q = 0; q < 4; q++){
        acc[2*q]   = fmaf((float)h0[q].x, a0, acc[2*q]);
        acc[2*q+1] = fmaf((float)h0[q].y, a0, acc[2*q+1]);
        acc[2*q]   = fmaf((float)h1[q].x, a1, acc[2*q]);
        acc[2*q+1] = fmaf((float)h1[q].y, a1, acc[2*q+1]);
        acc[2*q]   = fmaf((float)h2[q].x, a2, acc[2*q]);
        acc[2*q+1] = fmaf((float)h2[q].y, a2, acc[2*q+1]);
        acc[2*q]   = fmaf((float)h3[q].x, a3, acc[2*q]);
        acc[2*q+1] = fmaf((float)h3[q].y, a3, acc[2*q+1]);
      }
    } else {
      uint2 w0 = *(const uint2*)(fhbB + (((unsigned)s0 << 8) + cb));
      uint2 w1 = *(const uint2*)(fhbB + (((unsigned)s1 << 8) + cb));
      uint2 w2 = *(const uint2*)(fhbB + (((unsigned)s2 << 8) + cb));
      uint2 w3 = *(const uint2*)(fhbB + (((unsigned)s3 << 8) + cb));
      float e00 = __expf(fminf(lrelu(el0.x + er0), 30.f));
      float e10 = __expf(fminf(lrelu(el1.x + er0), 30.f));
      float e20 = __expf(fminf(lrelu(el2.x + er0), 30.f));
      float e30 = __expf(fminf(lrelu(el3.x + er0), 30.f));
      den0 += (e00 + e10) + (e20 + e30);
      const __half2* h0 = (const __half2*)&w0;
      const __half2* h1 = (const __half2*)&w1;
      const __half2* h2 = (const __half2*)&w2;
      const __half2* h3 = (const __half2*)&w3;
      #pragma unroll
      for (int q = 0; q < 2; q++){
        acc[2*q]   = fmaf((float)h0[q].x, e00, acc[2*q]);
        acc[2*q+1] = fmaf((float)h0[q].y, e00, acc[2*q+1]);
        acc[2*q]   = fmaf((float)h1[q].x, e10, acc[2*q]);
        acc[2*q+1] = fmaf((float)h1[q].y, e10, acc[2*q+1]);
        acc[2*q]   = fmaf((float)h2[q].x, e20, acc[2*q]);
        acc[2*q+1] = fmaf((float)h2[q].y, e20, acc[2*q+1]);
        acc[2*q]   = fmaf((float)h3[q].x, e30, acc[2*q]);
        acc[2*q+1] = fmaf((float)h3[q].y, e30, acc[2*q+1]);
      }
    }
  }
  for (; i < end; i++){                      // tail: 0-3 edges
    int s0 = ssrc[i];
    float2 el0 = *(const float2*)(elr + s0*4);
    float e00 = __expf(fminf(lrelu(el0.x + er0), 30.f));
    float e01 = (H == 2) ? __expf(fminf(lrelu(el0.y + er1), 30.f)) : 0.f;
    den0 += e00; den1 += e01;
    if (H == 2){
      uint4 w0 = *(const uint4*)(fhbB + (((unsigned)s0 << 8) + cb));
      float a0 = (c < 8) ? e00 : e01;
      const __half2* h0 = (const __half2*)&w0;
      #pragma unroll
      for (int q = 0; q < 4; q++){
        acc[2*q]   = fmaf((float)h0[q].x, a0, acc[2*q]);
        acc[2*q+1] = fmaf((float)h0[q].y, a0, acc[2*q+1]);
      }
    } else {
      uint2 w0 = *(const uint2*)(fhbB + (((unsigned)s0 << 8) + cb));
      const __half2* h0 = (const __half2*)&w0;
      #pragma unroll
      for (int q = 0; q < 2; q++){
        acc[2*q]   = fmaf((float)h0[q].x, e00, acc[2*q]);
        acc[2*q+1] = fmaf((float)h0[q].y, e00, acc[2*q+1]);
      }
    }
  }

  // epilogue: den identical across the group's lanes — no reduce needed.
  float rd0 = den0 > 0.f ? 1.f/den0 : 0.f;
  float rd1 = (H == 2 && den1 > 0.f) ? 1.f/den1 : 0.f;

  if (H == 2){
    float rs = (c < 8) ? rd0 : rd1;
    float o[8];
    const float4* b4 = (const float4*)(bias + c*8);
    float4 ba = b4[0], bb = b4[1];
    o[0]=fmaf(acc[0],rs,ba.x); o[1]=fmaf(acc[1],rs,ba.y);
    o[2]=fmaf(acc[2],rs,ba.z); o[3]=fmaf(acc[3],rs,ba.w);
    o[4]=fmaf(acc[4],rs,bb.x); o[5]=fmaf(acc[5],rs,bb.y);
    o[6]=fmaf(acc[6],rs,bb.z); o[7]=fmaf(acc[7],rs,bb.w);
    if (res){
      const float4* r4 = (const float4*)(res + (size_t)n*128 + c*8);
      float4 ra = r4[0], rb = r4[1];
      o[0]+=ra.x; o[1]+=ra.y; o[2]+=ra.z; o[3]+=ra.w;
      o[4]+=rb.x; o[5]+=rb.y; o[6]+=rb.z; o[7]+=rb.w;
    }
    if (act){
      #pragma unroll
      for (int k = 0; k < 8; k++) o[k] = elu1(o[k]);
    }
    if (out){
      float4* o4 = (float4*)(out + (size_t)n*out_ld + c*8);
      o4[0] = make_float4(o[0], o[1], o[2], o[3]);
      o4[1] = make_float4(o[4], o[5], o[6], o[7]);
    }
    if (outb){
      uint4 ob;
      ob.x = (unsigned)f2bf(o[0]) | ((unsigned)f2bf(o[1]) << 16);
      ob.y = (unsigned)f2bf(o[2]) | ((unsigned)f2bf(o[3]) << 16);
      ob.z = (unsigned)f2bf(o[4]) | ((unsigned)f2bf(o[5]) << 16);
      ob.w = (unsigned)f2bf(o[6]) | ((unsigned)f2bf(o[7]) << 16);
      *(uint4*)(outb + (size_t)n*64 + c*4) = ob;
    }
  } else {
    float o[4];
    #pragma unroll
    for (int k = 0; k < 4; k++) o[k] = fmaf(acc[k], rd0, bias[c*4 + k]);
    if (res_from_fh){
      uint2 r = *(const uint2*)(fhbB + (size_t)n*256 + 128 + c*8);
      const __half2* rp = (const __half2*)&r;
      o[0] += (float)rp[0].x; o[1] += (float)rp[0].y;
      o[2] += (float)rp[1].x; o[3] += (float)rp[1].y;
    }
    if (act){
      #pragma unroll
      for (int k = 0; k < 4; k++) o[k] = elu1(o[k]);
    }
    *(float4*)(out + (size_t)n*out_ld + c*4) = make_float4(o[0], o[1], o[2], o[3]);
  }
}

extern "C" void kernel_launch(void* const* d_in, const int* in_sizes, int n_in,
                              void* d_out, int out_size, void* d_ws, size_t ws_size,
                              hipStream_t stream) {
  const int*   feat = (const int*)  d_in[0];
  const float* fv   = (const float*)d_in[1];
  const int*   src  = (const int*)  d_in[2];
  const int*   dst  = (const int*)  d_in[3];
  const float* emb  = (const float*)d_in[4];
  const float* W0   = (const float*)d_in[5];
  const float* al0  = (const float*)d_in[6];
  const float* ar0  = (const float*)d_in[7];
  const float* b0   = (const float*)d_in[8];
  const float* W1   = (const float*)d_in[9];
  const float* al1  = (const float*)d_in[10];
  const float* ar1  = (const float*)d_in[11];
  const float* b1   = (const float*)d_in[12];
  const float* W2   = (const float*)d_in[13];
  const float* al2  = (const float*)d_in[14];
  const float* ar2  = (const float*)d_in[15];
  const float* b2   = (const float*)d_in[16];
  const float* rW2  = (const float*)d_in[17];
  const int N = in_sizes[0] / 8;   // 50000
  const int E = in_sizes[2];       // 800000

  size_t off = 0;
  auto alloc = [&](size_t bytes) -> void* {
    void* p = (char*)d_ws + off;
    off = (off + bytes + 255) & ~(size_t)255;
    return p;
  };
  unsigned short* P1 = (unsigned short*)alloc((size_t)N*128*sizeof(unsigned short)); // fhb f16
  float* P2     = (float*)alloc((size_t)N*128*sizeof(float));                        // layer0 out (res for layer1)
  unsigned short* hb = (unsigned short*)alloc((size_t)N*128*sizeof(unsigned short)); // h bf16
  float* elr    = (float*)alloc((size_t)N*4*sizeof(float));
  int* row_ptr  = (int*)alloc((size_t)(N+1)*sizeof(int));
  int* counts   = (int*)alloc((size_t)N*sizeof(int));
  int* rank     = (int*)alloc((size_t)E*sizeof(int));
  int* ssrc     = (int*)alloc((size_t)E*sizeof(int));
  int* perm     = (int*)alloc((size_t)N*sizeof(int));
  int* dcnt     = (int*)alloc(1024*sizeof(int));
  int* doff     = (int*)alloc(1024*sizeof(int));
  int* bsum     = (int*)alloc(256*sizeof(int));
  unsigned short* Wt0 = (unsigned short*)alloc((size_t)128*64*sizeof(unsigned short));
  unsigned short* Wt1 = (unsigned short*)alloc((size_t)128*128*sizeof(unsigned short));
  unsigned short* Wt2 = (unsigned short*)alloc((size_t)128*128*sizeof(unsigned short));

  int nb1 = (N + 255) / 256;
  int eb  = (E + 255) / 256;
  // setup: zero counts + degree bins + weight preps (one launch)
  k_setup<<<(N + 1024 + 128*64 + 2*128*128 + 255)/256, 256, 0, stream>>>(
      counts, dcnt, N, W0, W1, W2, rW2, Wt0, Wt1, Wt2);
  // CSR build (rank captured in hist atomic; scatter atomic-free)
  k_hist_rank<<<eb, 256, 0, stream>>>(dst, counts, rank, E);
  // degree counting sort (counts[n] = degree) -> perm
  k_deg_hist<<<nb1, 256, 0, stream>>>(counts, dcnt, N);
  k_deg_scan<<<1, 256, 0, stream>>>(dcnt, doff);
  k_deg_scatter<<<nb1, 256, 0, stream>>>(counts, doff, perm, N);
  k_scan_local<<<nb1, 256, 0, stream>>>(counts, row_ptr, bsum, N);
  k_scan_top<<<1, 256, 0, stream>>>(bsum, nb1);
  k_scan_fix<<<nb1, 256, 0, stream>>>(row_ptr, bsum, N);
  k_scatter2<<<eb, 256, 0, stream>>>(src, dst, rank, row_ptr, ssrc, E);

  int gt  = (N + 63)/64;
  int ngp = (N + 15)/16;
  // layer 0: in=64, H=2, embed fused into A-load, no residual, elu
  k_gemm_mfma<64,2,true><<<gt, 256, 0, stream>>>(nullptr, feat, fv, emb,
                                                 Wt0, al0, ar0, P1, elr, N);
  k_agg_gp<2><<<ngp, 256, 0, stream>>>(P1, elr, row_ptr, ssrc, perm, b0, nullptr,
                                       1, 0, P2, 128, (unsigned*)hb, N);
  // layer 1: in=128, H=2, identity residual, elu; float out unused -> skip store
  k_gemm_mfma<128,2,false><<<gt, 256, 0, stream>>>(hb, nullptr, nullptr, nullptr,
                                                   Wt1, al1, ar1, P1, elr, N);
  k_agg_gp<2><<<ngp, 256, 0, stream>>>(P1, elr, row_ptr, ssrc, perm, b1, P2,
                                       1, 0, nullptr, 128, (unsigned*)hb, N);
  // layer 2: in=128, H=1, projected residual (fh cols 64..127 = h@resW2), no act
  k_gemm_mfma<128,1,false><<<gt, 256, 0, stream>>>(hb, nullptr, nullptr, nullptr,
                                                   Wt2, al2, ar2, P1, elr, N);
  k_agg_gp<1><<<ngp, 256, 0, stream>>>(P1, elr, row_ptr, ssrc, perm, b2, nullptr,
                                       0, 1, (float*)d_out, 64, nullptr, N);
}

// Round 11
// 341.801 us; speedup vs baseline: 1.6980x; 1.6980x over previous
//
#include <hip/hip_runtime.h>
#include <hip/hip_fp16.h>

// GAT (3-layer) on MI355X. N=50000 nodes, E=800000 edges, D=64, H=2/2/1.
// R17 = R16's degree-sort hypothesis with the CONTENTION BUG fixed. R16's
//      k_deg_hist/scatter did 50000 global atomicAdd-with-return over ~40 hot
//      bins (Poisson(16) degrees) -> 131us each. Fix: two-level counting sort.
//      Phase A: per-block 64-bin LDS histogram captures local rank (LDS
//      atomics) + per-block bin counts to blkcnt[bin][block] (bin-major).
//      Phase B: one-block exclusive scan over 64*nb ints. Phase C: atomic-free
//      scatter perm[blkcnt[bin][blk]+lrank[n]] = n. ~10us total, once.
//      k_agg_gp unchanged from R16 (group -> perm[idx], uniform-degree blocks).

typedef __attribute__((ext_vector_type(8))) short short8;   // 8 bf16 (4 VGPRs)
typedef __attribute__((ext_vector_type(4))) float float4v;  // 4 fp32 acc

__device__ __forceinline__ float lrelu(float x){ return fmaxf(x, 0.2f*x); }

__device__ __forceinline__ unsigned short f2bf(float f){   // RNE round
  unsigned int u = __float_as_uint(f);
  u += 0x7fffu + ((u >> 16) & 1u);
  return (unsigned short)(u >> 16);
}
__device__ __forceinline__ unsigned short f2h(float f){
  return __half_as_ushort(__float2half(f));
}
__device__ __forceinline__ float elu1(float x){            // elu, x<0 branch via exp
  return x > 0.f ? x : (__expf(x) - 1.f);
}

// hist + rank in one atomic: rank[i] = position of edge i within its dst bucket
__global__ void k_hist_rank(const int* __restrict__ dst, int* __restrict__ counts,
                            int* __restrict__ rank, int E){
  int i = blockIdx.x*blockDim.x + threadIdx.x;
  if (i < E){
    int d = dst[i];
    rank[i] = atomicAdd(&counts[d], 1);
  }
}

__global__ void k_scan_local(const int* __restrict__ counts, int* __restrict__ row_ptr,
                             int* __restrict__ bsum, int N){
  __shared__ int s[256];
  int t = threadIdx.x, g = blockIdx.x*256 + t;
  int v = (g < N) ? counts[g] : 0;
  s[t] = v; __syncthreads();
  #pragma unroll
  for (int off = 1; off < 256; off <<= 1){
    int x = 0;
    if (t >= off) x = s[t-off];
    __syncthreads();
    s[t] += x;
    __syncthreads();
  }
  if (g < N) row_ptr[g+1] = s[t];
  if (g == 0 && t == 0) row_ptr[0] = 0;
  if (t == 255) bsum[blockIdx.x] = s[255];
}

__global__ void k_scan_top(int* __restrict__ bsum, int nb){
  __shared__ int s[256];
  int t = threadIdx.x;
  int v = (t < nb) ? bsum[t] : 0;
  s[t] = v; __syncthreads();
  #pragma unroll
  for (int off = 1; off < 256; off <<= 1){
    int x = 0;
    if (t >= off) x = s[t-off];
    __syncthreads();
    s[t] += x;
    __syncthreads();
  }
  if (t < nb) bsum[t] = s[t] - v;  // exclusive block offsets
}

__global__ void k_scan_fix(int* __restrict__ row_ptr, const int* __restrict__ bsum, int N){
  int g = blockIdx.x*256 + threadIdx.x;
  if (g < N && blockIdx.x > 0) row_ptr[g+1] += bsum[blockIdx.x];
}

// atomic-free scatter: pos comes from rank captured during hist
__global__ void k_scatter2(const int* __restrict__ src, const int* __restrict__ dst,
                           const int* __restrict__ rank, const int* __restrict__ row_ptr,
                           int* __restrict__ ssrc, int E){
  int i = blockIdx.x*blockDim.x + threadIdx.x;
  if (i < E) ssrc[row_ptr[dst[i]] + rank[i]] = src[i];
}

// ---- contention-free degree counting sort (counts[n] = degree) ----
// Phase A: LDS 64-bin histogram per block; local rank via LDS atomic;
// per-block counts to blkcnt[bin*nb + blk] (bin-major for the scan).
__global__ void k_deg_local(const int* __restrict__ counts, int* __restrict__ lrank,
                            int* __restrict__ blkcnt, int nb, int N){
  __shared__ int h[64];
  int t = threadIdx.x;
  if (t < 64) h[t] = 0;
  __syncthreads();
  int n = blockIdx.x*256 + t;
  if (n < N){
    int bin = min(counts[n], 63);
    lrank[n] = atomicAdd(&h[bin], 1);
  }
  __syncthreads();
  if (t < 64) blkcnt[t*nb + blockIdx.x] = h[t];
}

// Phase B: exclusive scan of blkcnt[0..total) in one 256-thread block.
__global__ void k_deg_scan2(int* __restrict__ blkcnt, int total){
  __shared__ int s[256];
  int t = threadIdx.x;
  int chunk = (total + 255) / 256;
  int b = t*chunk, e = min(b + chunk, total);
  int sum = 0;
  for (int i = b; i < e; i++) sum += blkcnt[i];
  s[t] = sum; __syncthreads();
  #pragma unroll
  for (int off = 1; off < 256; off <<= 1){
    int x = 0;
    if (t >= off) x = s[t-off];
    __syncthreads();
    s[t] += x;
    __syncthreads();
  }
  int base = (t == 0) ? 0 : s[t-1];
  for (int i = b; i < e; i++){ int v = blkcnt[i]; blkcnt[i] = base; base += v; }
}

// Phase C: atomic-free scatter into perm.
__global__ void k_deg_scatter2(const int* __restrict__ counts, const int* __restrict__ lrank,
                               const int* __restrict__ blkcnt, int nb,
                               int* __restrict__ perm, int N){
  int n = blockIdx.x*256 + threadIdx.x;
  if (n < N){
    int bin = min(counts[n], 63);
    perm[blkcnt[bin*nb + blockIdx.x] + lrank[n]] = n;
  }
}

// Fused setup: zero counts + all three weight preps.
// Wt layout: [n][IN] bf16 (n-major). W0: 64x128; W1: 128x128; W2|rW2: 128x(64+64).
__global__ void k_setup(int* __restrict__ counts, int N,
                        const float* __restrict__ W0, const float* __restrict__ W1,
                        const float* __restrict__ W2, const float* __restrict__ rW2,
                        unsigned short* __restrict__ Wt0, unsigned short* __restrict__ Wt1,
                        unsigned short* __restrict__ Wt2){
  int id = blockIdx.x*256 + threadIdx.x;
  if (id < N){ counts[id] = 0; return; }
  int j = id - N;
  if (j < 128*64){
    int n = j/64, k = j%64;
    Wt0[n*64 + k] = f2bf(W0[k*128 + n]);
  } else if (j < 128*64 + 128*128){
    int i = j - 128*64; int n = i/128, k = i%128;
    Wt1[n*128 + k] = f2bf(W1[k*128 + n]);
  } else if (j < 128*64 + 2*128*128){
    int i = j - 128*64 - 128*128; int n = i/128, k = i%128;
    float v = (n < 64) ? W2[k*64 + n] : rW2[k*64 + (n - 64)];
    Wt2[n*128 + k] = f2bf(v);
  }
}

// MFMA GEMM: fhb[N][128](f16 row-major) = A[N][IN] @ W(128 cols via Wt).
// A source: hb bf16 (EMBED=false) or emb[feat[n]]*fv[n] converted on the fly
// (EMBED=true, IN==64). Block 256 thr = 4 waves; wave: 16 rows x 128 cols.
// Layouts (verified): A[m=lane&15][k=quad*8+j]; B[k=quad*8+j][n=lane&15];
// D: col=lane&15, row=quad*4+reg. el/er fused (16-lane butterfly per quad).
template<int IN, int H, bool EMBED>
__global__ __launch_bounds__(256) void k_gemm_mfma(
    const unsigned short* __restrict__ hb,   // [N][IN] bf16 (unused if EMBED)
    const int* __restrict__ feat, const float* __restrict__ fv,
    const float* __restrict__ embp,          // [VOCAB][64] f32
    const unsigned short* __restrict__ Wt,   // [128][IN] bf16, n-major
    const float* __restrict__ al, const float* __restrict__ ar,
    unsigned short* __restrict__ fhb,        // [N][128] f16
    float* __restrict__ elr, int N){
  constexpr int KS = IN/32;
  constexpr int LDP = IN + 8;                // +8 bf16 pad: 2-way banks only
  __shared__ unsigned short Wt_s[128*LDP];
  const int t = threadIdx.x;
  const int lane = t & 63, wid = t >> 6;
  const int l15 = lane & 15, quad = lane >> 4;
  const int row0 = blockIdx.x*64 + wid*16;

  // stage Wt -> LDS (uint4 = 8 bf16)
  for (int id = t; id < 128*(IN/8); id += 256){
    int r = id/(IN/8), seg = id%(IN/8);
    ((uint4*)(Wt_s + r*LDP))[seg] = ((const uint4*)(Wt + (size_t)r*IN))[seg];
  }
  // A fragments from global (overlaps LDS staging)
  short8 a[KS];
  int arow = row0 + l15;
  if (EMBED){
    if (arow < N){
      const float* er2 = embp + (size_t)feat[arow]*64;
      float sc = fv[arow];
      #pragma unroll
      for (int s = 0; s < KS; s++){
        const float4* p = (const float4*)(er2 + s*32 + quad*8);
        float4 v0 = p[0], v1 = p[1];
        short8 ta;
        ta[0] = (short)f2bf(v0.x*sc); ta[1] = (short)f2bf(v0.y*sc);
        ta[2] = (short)f2bf(v0.z*sc); ta[3] = (short)f2bf(v0.w*sc);
        ta[4] = (short)f2bf(v1.x*sc); ta[5] = (short)f2bf(v1.y*sc);
        ta[6] = (short)f2bf(v1.z*sc); ta[7] = (short)f2bf(v1.w*sc);
        a[s] = ta;
      }
    } else {
      #pragma unroll
      for (int s = 0; s < KS; s++) a[s] = short8{0,0,0,0,0,0,0,0};
    }
  } else {
    #pragma unroll
    for (int s = 0; s < KS; s++){
      if (arow < N) a[s] = *(const short8*)(hb + (size_t)arow*IN + s*32 + quad*8);
      else          a[s] = short8{0,0,0,0,0,0,0,0};
    }
  }
  __syncthreads();

  float4v acc[8];
  #pragma unroll
  for (int nt = 0; nt < 8; nt++) acc[nt] = float4v{0.f,0.f,0.f,0.f};
  #pragma unroll
  for (int nt = 0; nt < 8; nt++){
    #pragma unroll
    for (int s = 0; s < KS; s++){
      short8 b = *(const short8*)(Wt_s + (nt*16 + l15)*LDP + s*32 + quad*8);
      acc[nt] = __builtin_amdgcn_mfma_f32_16x16x32_bf16(a[s], b, acc[nt], 0, 0, 0);
    }
  }

  // al/ar at this lane's columns (col = nt*16 + l15); H==1: heads>0 are zero
  float alc[8], arc[8];
  #pragma unroll
  for (int nt = 0; nt < 8; nt++){
    bool hv = (H == 2) || (nt < 4);
    alc[nt] = hv ? al[nt*16 + l15] : 0.f;
    arc[nt] = hv ? ar[nt*16 + l15] : 0.f;
  }
  #pragma unroll
  for (int reg = 0; reg < 4; reg++){
    int row = row0 + quad*4 + reg;
    bool rv = row < N;
    if (rv){
      #pragma unroll
      for (int nt = 0; nt < 8; nt++)
        fhb[(size_t)row*128 + nt*16 + l15] = f2h(acc[nt][reg]);
    }
    float pel0 = 0.f, per0 = 0.f, pel1 = 0.f, per1 = 0.f;
    #pragma unroll
    for (int nt = 0; nt < 4; nt++){
      pel0 += acc[nt][reg]*alc[nt];     per0 += acc[nt][reg]*arc[nt];
      pel1 += acc[nt+4][reg]*alc[nt+4]; per1 += acc[nt+4][reg]*arc[nt+4];
    }
    #pragma unroll
    for (int off = 1; off < 16; off <<= 1){   // reduce across the 16 lanes of a quad
      pel0 += __shfl_xor(pel0, off, 64);
      pel1 += __shfl_xor(pel1, off, 64);
      per0 += __shfl_xor(per0, off, 64);
      per1 += __shfl_xor(per1, off, 64);
    }
    if (l15 == 0 && rv){
      elr[row*4+0] = pel0;
      elr[row*4+1] = (H == 2) ? pel1 : 0.f;
      elr[row*4+2] = per0;
      elr[row*4+3] = (H == 2) ? per1 : 0.f;
    }
  }
}

// GROUP-PER-NODE aggregation: block = 256 thr = 16 groups of 16 lanes; each
// group owns ONE node (via degree-sorted perm -> uniform trip counts within
// a block) and streams its edges. Lane c holds a 16B (H=2, full 256B row) /
// 8B (H=1, cols 0..63) chunk. alpha computed inline per edge (same value in
// all 16 lanes — no cross-lane ops anywhere). den accumulates identically per
// lane -> epilogue reciprocal needs no reduce. 4-deep main loop: 4 independent
// ssrc->elr->row chains, 12 VMEM in flight.
template<int H>
__global__ __launch_bounds__(256) void k_agg_gp(
    const unsigned short* __restrict__ fhb,  // [N][128] f16
    const float* __restrict__ elr,           // [N][4]
    const int* __restrict__ row_ptr, const int* __restrict__ ssrc,
    const int* __restrict__ perm,            // degree-sorted node ids
    const float* __restrict__ bias, const float* __restrict__ res,
    int act, int res_from_fh,
    float* __restrict__ out, int out_ld, unsigned* __restrict__ outb, int N){
  const int t = threadIdx.x;
  const int gq = t >> 4, c = t & 15;         // group, lane-in-group
  const int idx = blockIdx.x*16 + gq;
  if (idx >= N) return;
  const int n = perm[idx];
  const int beg = row_ptr[n], end = row_ptr[n+1];
  const float er0 = elr[n*4+2];
  const float er1 = (H == 2) ? elr[n*4+3] : 0.f;

  const char* fhbB = (const char*)fhb;       // row = 256 B, 32-bit offsets
  const unsigned cb = (H == 2) ? ((unsigned)c << 4) : ((unsigned)c << 3);
  constexpr int PC = (H == 2) ? 8 : 4;       // cols per lane

  float acc[PC];
  #pragma unroll
  for (int k = 0; k < PC; k++) acc[k] = 0.f;
  float den0 = 0.f, den1 = 0.f;

  int i = beg;
  for (; i + 3 < end; i += 4){               // 4-deep: 4 independent chains
    int s0 = ssrc[i],   s1 = ssrc[i+1];
    int s2 = ssrc[i+2], s3 = ssrc[i+3];
    float2 el0 = *(const float2*)(elr + s0*4);
    float2 el1 = *(const float2*)(elr + s1*4);
    float2 el2 = *(const float2*)(elr + s2*4);
    float2 el3 = *(const float2*)(elr + s3*4);
    if (H == 2){
      uint4 w0 = *(const uint4*)(fhbB + (((unsigned)s0 << 8) + cb));
      uint4 w1 = *(const uint4*)(fhbB + (((unsigned)s1 << 8) + cb));
      uint4 w2 = *(const uint4*)(fhbB + (((unsigned)s2 << 8) + cb));
      uint4 w3 = *(const uint4*)(fhbB + (((unsigned)s3 << 8) + cb));
      float e00 = __expf(fminf(lrelu(el0.x + er0), 30.f));
      float e10 = __expf(fminf(lrelu(el1.x + er0), 30.f));
      float e20 = __expf(fminf(lrelu(el2.x + er0), 30.f));
      float e30 = __expf(fminf(lrelu(el3.x + er0), 30.f));
      float e01 = __expf(fminf(lrelu(el0.y + er1), 30.f));
      float e11 = __expf(fminf(lrelu(el1.y + er1), 30.f));
      float e21 = __expf(fminf(lrelu(el2.y + er1), 30.f));
      float e31 = __expf(fminf(lrelu(el3.y + er1), 30.f));
      den0 += (e00 + e10) + (e20 + e30);
      den1 += (e01 + e11) + (e21 + e31);
      float a0 = (c < 8) ? e00 : e01;        // head = col/64
      float a1 = (c < 8) ? e10 : e11;
      float a2 = (c < 8) ? e20 : e21;
      float a3 = (c < 8) ? e30 : e31;
      const __half2* h0 = (const __half2*)&w0;
      const __half2* h1 = (const __half2*)&w1;
      const __half2* h2 = (const __half2*)&w2;
      const __half2* h3 = (const __half2*)&w3;
      #pragma unroll
      for (int q = 0; q < 4; q++){
        acc[2*q]   = fmaf((float)h0[q].x, a0, acc[2*q]);
        acc[2*q+1] = fmaf((float)h0[q].y, a0, acc[2*q+1]);
        acc[2*q]   = fmaf((float)h1[q].x, a1, acc[2*q]);
        acc[2*q+1] = fmaf((float)h1[q].y, a1, acc[2*q+1]);
        acc[2*q]   = fmaf((float)h2[q].x, a2, acc[2*q]);
        acc[2*q+1] = fmaf((float)h2[q].y, a2, acc[2*q+1]);
        acc[2*q]   = fmaf((float)h3[q].x, a3, acc[2*q]);
        acc[2*q+1] = fmaf((float)h3[q].y, a3, acc[2*q+1]);
      }
    } else {
      uint2 w0 = *(const uint2*)(fhbB + (((unsigned)s0 << 8) + cb));
      uint2 w1 = *(const uint2*)(fhbB + (((unsigned)s1 << 8) + cb));
      uint2 w2 = *(const uint2*)(fhbB + (((unsigned)s2 << 8) + cb));
      uint2 w3 = *(const uint2*)(fhbB + (((unsigned)s3 << 8) + cb));
      float e00 = __expf(fminf(lrelu(el0.x + er0), 30.f));
      float e10 = __expf(fminf(lrelu(el1.x + er0), 30.f));
      float e20 = __expf(fminf(lrelu(el2.x + er0), 30.f));
      float e30 = __expf(fminf(lrelu(el3.x + er0), 30.f));
      den0 += (e00 + e10) + (e20 + e30);
      const __half2* h0 = (const __half2*)&w0;
      const __half2* h1 = (const __half2*)&w1;
      const __half2* h2 = (const __half2*)&w2;
      const __half2* h3 = (const __half2*)&w3;
      #pragma unroll
      for (int q = 0; q < 2; q++){
        acc[2*q]   = fmaf((float)h0[q].x, e00, acc[2*q]);
        acc[2*q+1] = fmaf((float)h0[q].y, e00, acc[2*q+1]);
        acc[2*q]   = fmaf((float)h1[q].x, e10, acc[2*q]);
        acc[2*q+1] = fmaf((float)h1[q].y, e10, acc[2*q+1]);
        acc[2*q]   = fmaf((float)h2[q].x, e20, acc[2*q]);
        acc[2*q+1] = fmaf((float)h2[q].y, e20, acc[2*q+1]);
        acc[2*q]   = fmaf((float)h3[q].x, e30, acc[2*q]);
        acc[2*q+1] = fmaf((float)h3[q].y, e30, acc[2*q+1]);
      }
    }
  }
  for (; i < end; i++){                      // tail: 0-3 edges
    int s0 = ssrc[i];
    float2 el0 = *(const float2*)(elr + s0*4);
    float e00 = __expf(fminf(lrelu(el0.x + er0), 30.f));
    float e01 = (H == 2) ? __expf(fminf(lrelu(el0.y + er1), 30.f)) : 0.f;
    den0 += e00; den1 += e01;
    if (H == 2){
      uint4 w0 = *(const uint4*)(fhbB + (((unsigned)s0 << 8) + cb));
      float a0 = (c < 8) ? e00 : e01;
      const __half2* h0 = (const __half2*)&w0;
      #pragma unroll
      for (int q = 0; q < 4; q++){
        acc[2*q]   = fmaf((float)h0[q].x, a0, acc[2*q]);
        acc[2*q+1] = fmaf((float)h0[q].y, a0, acc[2*q+1]);
      }
    } else {
      uint2 w0 = *(const uint2*)(fhbB + (((unsigned)s0 << 8) + cb));
      const __half2* h0 = (const __half2*)&w0;
      #pragma unroll
      for (int q = 0; q < 2; q++){
        acc[2*q]   = fmaf((float)h0[q].x, e00, acc[2*q]);
        acc[2*q+1] = fmaf((float)h0[q].y, e00, acc[2*q+1]);
      }
    }
  }

  // epilogue: den identical across the group's lanes — no reduce needed.
  float rd0 = den0 > 0.f ? 1.f/den0 : 0.f;
  float rd1 = (H == 2 && den1 > 0.f) ? 1.f/den1 : 0.f;

  if (H == 2){
    float rs = (c < 8) ? rd0 : rd1;
    float o[8];
    const float4* b4 = (const float4*)(bias + c*8);
    float4 ba = b4[0], bb = b4[1];
    o[0]=fmaf(acc[0],rs,ba.x); o[1]=fmaf(acc[1],rs,ba.y);
    o[2]=fmaf(acc[2],rs,ba.z); o[3]=fmaf(acc[3],rs,ba.w);
    o[4]=fmaf(acc[4],rs,bb.x); o[5]=fmaf(acc[5],rs,bb.y);
    o[6]=fmaf(acc[6],rs,bb.z); o[7]=fmaf(acc[7],rs,bb.w);
    if (res){
      const float4* r4 = (const float4*)(res + (size_t)n*128 + c*8);
      float4 ra = r4[0], rb = r4[1];
      o[0]+=ra.x; o[1]+=ra.y; o[2]+=ra.z; o[3]+=ra.w;
      o[4]+=rb.x; o[5]+=rb.y; o[6]+=rb.z; o[7]+=rb.w;
    }
    if (act){
      #pragma unroll
      for (int k = 0; k < 8; k++) o[k] = elu1(o[k]);
    }
    if (out){
      float4* o4 = (float4*)(out + (size_t)n*out_ld + c*8);
      o4[0] = make_float4(o[0], o[1], o[2], o[3]);
      o4[1] = make_float4(o[4], o[5], o[6], o[7]);
    }
    if (outb){
      uint4 ob;
      ob.x = (unsigned)f2bf(o[0]) | ((unsigned)f2bf(o[1]) << 16);
      ob.y = (unsigned)f2bf(o[2]) | ((unsigned)f2bf(o[3]) << 16);
      ob.z = (unsigned)f2bf(o[4]) | ((unsigned)f2bf(o[5]) << 16);
      ob.w = (unsigned)f2bf(o[6]) | ((unsigned)f2bf(o[7]) << 16);
      *(uint4*)(outb + (size_t)n*64 + c*4) = ob;
    }
  } else {
    float o[4];
    #pragma unroll
    for (int k = 0; k < 4; k++) o[k] = fmaf(acc[k], rd0, bias[c*4 + k]);
    if (res_from_fh){
      uint2 r = *(const uint2*)(fhbB + (size_t)n*256 + 128 + c*8);
      const __half2* rp = (const __half2*)&r;
      o[0] += (float)rp[0].x; o[1] += (float)rp[0].y;
      o[2] += (float)rp[1].x; o[3] += (float)rp[1].y;
    }
    if (act){
      #pragma unroll
      for (int k = 0; k < 4; k++) o[k] = elu1(o[k]);
    }
    *(float4*)(out + (size_t)n*out_ld + c*4) = make_float4(o[0], o[1], o[2], o[3]);
  }
}

extern "C" void kernel_launch(void* const* d_in, const int* in_sizes, int n_in,
                              void* d_out, int out_size, void* d_ws, size_t ws_size,
                              hipStream_t stream) {
  const int*   feat = (const int*)  d_in[0];
  const float* fv   = (const float*)d_in[1];
  const int*   src  = (const int*)  d_in[2];
  const int*   dst  = (const int*)  d_in[3];
  const float* emb  = (const float*)d_in[4];
  const float* W0   = (const float*)d_in[5];
  const float* al0  = (const float*)d_in[6];
  const float* ar0  = (const float*)d_in[7];
  const float* b0   = (const float*)d_in[8];
  const float* W1   = (const float*)d_in[9];
  const float* al1  = (const float*)d_in[10];
  const float* ar1  = (const float*)d_in[11];
  const float* b1   = (const float*)d_in[12];
  const float* W2   = (const float*)d_in[13];
  const float* al2  = (const float*)d_in[14];
  const float* ar2  = (const float*)d_in[15];
  const float* b2   = (const float*)d_in[16];
  const float* rW2  = (const float*)d_in[17];
  const int N = in_sizes[0] / 8;   // 50000
  const int E = in_sizes[2];       // 800000

  size_t off = 0;
  auto alloc = [&](size_t bytes) -> void* {
    void* p = (char*)d_ws + off;
    off = (off + bytes + 255) & ~(size_t)255;
    return p;
  };
  unsigned short* P1 = (unsigned short*)alloc((size_t)N*128*sizeof(unsigned short)); // fhb f16
  float* P2     = (float*)alloc((size_t)N*128*sizeof(float));                        // layer0 out (res for layer1)
  unsigned short* hb = (unsigned short*)alloc((size_t)N*128*sizeof(unsigned short)); // h bf16
  float* elr    = (float*)alloc((size_t)N*4*sizeof(float));
  int* row_ptr  = (int*)alloc((size_t)(N+1)*sizeof(int));
  int* counts   = (int*)alloc((size_t)N*sizeof(int));
  int* rank     = (int*)alloc((size_t)E*sizeof(int));
  int* ssrc     = (int*)alloc((size_t)E*sizeof(int));
  int* perm     = (int*)alloc((size_t)N*sizeof(int));
  int* lrank    = (int*)alloc((size_t)N*sizeof(int));
  int nb1 = (N + 255) / 256;
  int* blkcnt   = (int*)alloc((size_t)64*nb1*sizeof(int));
  int* bsum     = (int*)alloc(256*sizeof(int));
  unsigned short* Wt0 = (unsigned short*)alloc((size_t)128*64*sizeof(unsigned short));
  unsigned short* Wt1 = (unsigned short*)alloc((size_t)128*128*sizeof(unsigned short));
  unsigned short* Wt2 = (unsigned short*)alloc((size_t)128*128*sizeof(unsigned short));

  int eb  = (E + 255) / 256;
  // setup: zero counts + weight preps (one launch)
  k_setup<<<(N + 128*64 + 2*128*128 + 255)/256, 256, 0, stream>>>(
      counts, N, W0, W1, W2, rW2, Wt0, Wt1, Wt2);
  // CSR build (rank captured in hist atomic; scatter atomic-free)
  k_hist_rank<<<eb, 256, 0, stream>>>(dst, counts, rank, E);
  // contention-free degree counting sort (counts[n] = degree) -> perm
  k_deg_local<<<nb1, 256, 0, stream>>>(counts, lrank, blkcnt, nb1, N);
  k_deg_scan2<<<1, 256, 0, stream>>>(blkcnt, 64*nb1);
  k_deg_scatter2<<<nb1, 256, 0, stream>>>(counts, lrank, blkcnt, nb1, perm, N);
  k_scan_local<<<nb1, 256, 0, stream>>>(counts, row_ptr, bsum, N);
  k_scan_top<<<1, 256, 0, stream>>>(bsum, nb1);
  k_scan_fix<<<nb1, 256, 0, stream>>>(row_ptr, bsum, N);
  k_scatter2<<<eb, 256, 0, stream>>>(src, dst, rank, row_ptr, ssrc, E);

  int gt  = (N + 63)/64;
  int ngp = (N + 15)/16;
  // layer 0: in=64, H=2, embed fused into A-load, no residual, elu
  k_gemm_mfma<64,2,true><<<gt, 256, 0, stream>>>(nullptr, feat, fv, emb,
                                                 Wt0, al0, ar0, P1, elr, N);
  k_agg_gp<2><<<ngp, 256, 0, stream>>>(P1, elr, row_ptr, ssrc, perm, b0, nullptr,
                                       1, 0, P2, 128, (unsigned*)hb, N);
  // layer 1: in=128, H=2, identity residual, elu; float out unused -> skip store
  k_gemm_mfma<128,2,false><<<gt, 256, 0, stream>>>(hb, nullptr, nullptr, nullptr,
                                                   Wt1, al1, ar1, P1, elr, N);
  k_agg_gp<2><<<ngp, 256, 0, stream>>>(P1, elr, row_ptr, ssrc, perm, b1, P2,
                                       1, 0, nullptr, 128, (unsigned*)hb, N);
  // layer 2: in=128, H=1, projected residual (fh cols 64..127 = h@resW2), no act
  k_gemm_mfma<128,1,false><<<gt, 256, 0, stream>>>(hb, nullptr, nullptr, nullptr,
                                                   Wt2, al2, ar2, P1, elr, N);
  k_agg_gp<1><<<ngp, 256, 0, stream>>>(P1, elr, row_ptr, ssrc, perm, b2, nullptr,
                                       0, 1, (float*)d_out, 64, nullptr, N);
}

// Round 12
// 308.222 us; speedup vs baseline: 1.8830x; 1.1089x over previous
//
#include <hip/hip_runtime.h>
#include <hip/hip_fp16.h>

// GAT (3-layer) on MI355X. N=50000 nodes, E=800000 edges, D=64, H=2/2/1.
// R18: R17 degree-sort REVERTED (k_agg_gp unchanged at 41us with uniform
//      blocks -> imbalance hypothesis falsified; perm cost locality, FETCH
//      91->110MB, +28us). k_agg is pinned 41-46us across 7 structures =
//      random-256B-gather memory floor; accepted. New lever: critical-path
//      overlap — k_hist_rank (800K atomics, independent of GEMM0) fused into
//      GEMM0's launch via block partition (blockIdx<gt: gemm0, else: hist).
//      GEMM body factored to a __device__ fn; IN=128 GEMMs untouched (R15).

typedef __attribute__((ext_vector_type(8))) short short8;   // 8 bf16 (4 VGPRs)
typedef __attribute__((ext_vector_type(4))) float float4v;  // 4 fp32 acc

__device__ __forceinline__ float lrelu(float x){ return fmaxf(x, 0.2f*x); }

__device__ __forceinline__ unsigned short f2bf(float f){   // RNE round
  unsigned int u = __float_as_uint(f);
  u += 0x7fffu + ((u >> 16) & 1u);
  return (unsigned short)(u >> 16);
}
__device__ __forceinline__ unsigned short f2h(float f){
  return __half_as_ushort(__float2half(f));
}
__device__ __forceinline__ float elu1(float x){            // elu, x<0 branch via exp
  return x > 0.f ? x : (__expf(x) - 1.f);
}

__global__ void k_scan_local(const int* __restrict__ counts, int* __restrict__ row_ptr,
                             int* __restrict__ bsum, int N){
  __shared__ int s[256];
  int t = threadIdx.x, g = blockIdx.x*256 + t;
  int v = (g < N) ? counts[g] : 0;
  s[t] = v; __syncthreads();
  #pragma unroll
  for (int off = 1; off < 256; off <<= 1){
    int x = 0;
    if (t >= off) x = s[t-off];
    __syncthreads();
    s[t] += x;
    __syncthreads();
  }
  if (g < N) row_ptr[g+1] = s[t];
  if (g == 0 && t == 0) row_ptr[0] = 0;
  if (t == 255) bsum[blockIdx.x] = s[255];
}

__global__ void k_scan_top(int* __restrict__ bsum, int nb){
  __shared__ int s[256];
  int t = threadIdx.x;
  int v = (t < nb) ? bsum[t] : 0;
  s[t] = v; __syncthreads();
  #pragma unroll
  for (int off = 1; off < 256; off <<= 1){
    int x = 0;
    if (t >= off) x = s[t-off];
    __syncthreads();
    s[t] += x;
    __syncthreads();
  }
  if (t < nb) bsum[t] = s[t] - v;  // exclusive block offsets
}

__global__ void k_scan_fix(int* __restrict__ row_ptr, const int* __restrict__ bsum, int N){
  int g = blockIdx.x*256 + threadIdx.x;
  if (g < N && blockIdx.x > 0) row_ptr[g+1] += bsum[blockIdx.x];
}

// atomic-free scatter: pos comes from rank captured during hist
__global__ void k_scatter2(const int* __restrict__ src, const int* __restrict__ dst,
                           const int* __restrict__ rank, const int* __restrict__ row_ptr,
                           int* __restrict__ ssrc, int E){
  int i = blockIdx.x*blockDim.x + threadIdx.x;
  if (i < E) ssrc[row_ptr[dst[i]] + rank[i]] = src[i];
}

// Fused setup: zero counts + all three weight preps (independent elementwise).
// Wt layout: [n][IN] bf16 (n-major). W0: 64x128; W1: 128x128; W2|rW2: 128x(64+64).
__global__ void k_setup(int* __restrict__ counts, int N,
                        const float* __restrict__ W0, const float* __restrict__ W1,
                        const float* __restrict__ W2, const float* __restrict__ rW2,
                        unsigned short* __restrict__ Wt0, unsigned short* __restrict__ Wt1,
                        unsigned short* __restrict__ Wt2){
  int id = blockIdx.x*256 + threadIdx.x;
  if (id < N){ counts[id] = 0; return; }
  int j = id - N;
  if (j < 128*64){
    int n = j/64, k = j%64;
    Wt0[n*64 + k] = f2bf(W0[k*128 + n]);
  } else if (j < 128*64 + 128*128){
    int i = j - 128*64; int n = i/128, k = i%128;
    Wt1[n*128 + k] = f2bf(W1[k*128 + n]);
  } else if (j < 128*64 + 2*128*128){
    int i = j - 128*64 - 128*128; int n = i/128, k = i%128;
    float v = (n < 64) ? W2[k*64 + n] : rW2[k*64 + (n - 64)];
    Wt2[n*128 + k] = f2bf(v);
  }
}

// MFMA GEMM body: fhb[N][128](f16 row-major) = A[N][IN] @ W(128 cols via Wt).
// A source: hb bf16 (EMBED=false) or emb[feat[n]]*fv[n] converted on the fly
// (EMBED=true, IN==64). 256 thr = 4 waves; block bid covers 64 rows.
// Layouts (verified): A[m=lane&15][k=quad*8+j]; B[k=quad*8+j][n=lane&15];
// D: col=lane&15, row=quad*4+reg. el/er fused (16-lane butterfly per quad).
template<int IN, int H, bool EMBED>
__device__ __forceinline__ void gemm_body(
    unsigned short* __restrict__ Wt_s,       // [128*(IN+8)] LDS
    const unsigned short* __restrict__ hb,
    const int* __restrict__ feat, const float* __restrict__ fv,
    const float* __restrict__ embp,
    const unsigned short* __restrict__ Wt,
    const float* __restrict__ al, const float* __restrict__ ar,
    unsigned short* __restrict__ fhb,
    float* __restrict__ elr, int N, int bid){
  constexpr int KS = IN/32;
  constexpr int LDP = IN + 8;                // +8 bf16 pad: 2-way banks only
  const int t = threadIdx.x;
  const int lane = t & 63, wid = t >> 6;
  const int l15 = lane & 15, quad = lane >> 4;
  const int row0 = bid*64 + wid*16;

  // stage Wt -> LDS (uint4 = 8 bf16)
  for (int id = t; id < 128*(IN/8); id += 256){
    int r = id/(IN/8), seg = id%(IN/8);
    ((uint4*)(Wt_s + r*LDP))[seg] = ((const uint4*)(Wt + (size_t)r*IN))[seg];
  }
  // A fragments from global (overlaps LDS staging)
  short8 a[KS];
  int arow = row0 + l15;
  if (EMBED){
    if (arow < N){
      const float* er2 = embp + (size_t)feat[arow]*64;
      float sc = fv[arow];
      #pragma unroll
      for (int s = 0; s < KS; s++){
        const float4* p = (const float4*)(er2 + s*32 + quad*8);
        float4 v0 = p[0], v1 = p[1];
        short8 ta;
        ta[0] = (short)f2bf(v0.x*sc); ta[1] = (short)f2bf(v0.y*sc);
        ta[2] = (short)f2bf(v0.z*sc); ta[3] = (short)f2bf(v0.w*sc);
        ta[4] = (short)f2bf(v1.x*sc); ta[5] = (short)f2bf(v1.y*sc);
        ta[6] = (short)f2bf(v1.z*sc); ta[7] = (short)f2bf(v1.w*sc);
        a[s] = ta;
      }
    } else {
      #pragma unroll
      for (int s = 0; s < KS; s++) a[s] = short8{0,0,0,0,0,0,0,0};
    }
  } else {
    #pragma unroll
    for (int s = 0; s < KS; s++){
      if (arow < N) a[s] = *(const short8*)(hb + (size_t)arow*IN + s*32 + quad*8);
      else          a[s] = short8{0,0,0,0,0,0,0,0};
    }
  }
  __syncthreads();

  float4v acc[8];
  #pragma unroll
  for (int nt = 0; nt < 8; nt++) acc[nt] = float4v{0.f,0.f,0.f,0.f};
  #pragma unroll
  for (int nt = 0; nt < 8; nt++){
    #pragma unroll
    for (int s = 0; s < KS; s++){
      short8 b = *(const short8*)(Wt_s + (nt*16 + l15)*LDP + s*32 + quad*8);
      acc[nt] = __builtin_amdgcn_mfma_f32_16x16x32_bf16(a[s], b, acc[nt], 0, 0, 0);
    }
  }

  // al/ar at this lane's columns (col = nt*16 + l15); H==1: heads>0 are zero
  float alc[8], arc[8];
  #pragma unroll
  for (int nt = 0; nt < 8; nt++){
    bool hv = (H == 2) || (nt < 4);
    alc[nt] = hv ? al[nt*16 + l15] : 0.f;
    arc[nt] = hv ? ar[nt*16 + l15] : 0.f;
  }
  #pragma unroll
  for (int reg = 0; reg < 4; reg++){
    int row = row0 + quad*4 + reg;
    bool rv = row < N;
    if (rv){
      #pragma unroll
      for (int nt = 0; nt < 8; nt++)
        fhb[(size_t)row*128 + nt*16 + l15] = f2h(acc[nt][reg]);
    }
    float pel0 = 0.f, per0 = 0.f, pel1 = 0.f, per1 = 0.f;
    #pragma unroll
    for (int nt = 0; nt < 4; nt++){
      pel0 += acc[nt][reg]*alc[nt];     per0 += acc[nt][reg]*arc[nt];
      pel1 += acc[nt+4][reg]*alc[nt+4]; per1 += acc[nt+4][reg]*arc[nt+4];
    }
    #pragma unroll
    for (int off = 1; off < 16; off <<= 1){   // reduce across the 16 lanes of a quad
      pel0 += __shfl_xor(pel0, off, 64);
      pel1 += __shfl_xor(pel1, off, 64);
      per0 += __shfl_xor(per0, off, 64);
      per1 += __shfl_xor(per1, off, 64);
    }
    if (l15 == 0 && rv){
      elr[row*4+0] = pel0;
      elr[row*4+1] = (H == 2) ? pel1 : 0.f;
      elr[row*4+2] = per0;
      elr[row*4+3] = (H == 2) ? per1 : 0.f;
    }
  }
}

// Standalone GEMM (layers 1 and 2, IN=128)
template<int IN, int H, bool EMBED>
__global__ __launch_bounds__(256) void k_gemm_mfma(
    const unsigned short* __restrict__ hb,
    const int* __restrict__ feat, const float* __restrict__ fv,
    const float* __restrict__ embp,
    const unsigned short* __restrict__ Wt,
    const float* __restrict__ al, const float* __restrict__ ar,
    unsigned short* __restrict__ fhb,
    float* __restrict__ elr, int N){
  __shared__ unsigned short Wt_s[128*(IN + 8)];
  gemm_body<IN,H,EMBED>(Wt_s, hb, feat, fv, embp, Wt, al, ar, fhb, elr, N,
                        blockIdx.x);
}

// Fused layer-0 GEMM + edge histogram: blocks [0,gt) run the EMBED gemm
// (independent of CSR), blocks [gt, gt+eb) run hist_rank (needs only zeroed
// counts from k_setup). Overlaps ~10-15us of 800K global atomics under GEMM0.
__global__ __launch_bounds__(256) void k_gemm0_hist(
    const int* __restrict__ feat, const float* __restrict__ fv,
    const float* __restrict__ embp,
    const unsigned short* __restrict__ Wt,
    const float* __restrict__ al, const float* __restrict__ ar,
    unsigned short* __restrict__ fhb, float* __restrict__ elr, int N, int gt,
    const int* __restrict__ dst, int* __restrict__ counts,
    int* __restrict__ rank, int E){
  __shared__ unsigned short Wt_s[128*(64 + 8)];
  if ((int)blockIdx.x < gt){
    gemm_body<64,2,true>(Wt_s, nullptr, feat, fv, embp, Wt, al, ar, fhb, elr,
                         N, blockIdx.x);
  } else {
    int i = ((int)blockIdx.x - gt)*256 + threadIdx.x;
    if (i < E){
      int d = dst[i];
      rank[i] = atomicAdd(&counts[d], 1);
    }
  }
}

// GROUP-PER-NODE aggregation: block = 256 thr = 16 groups of 16 lanes; each
// group owns ONE node and streams its edges. Lane c holds a 16B (H=2, full
// 256B row) / 8B (H=1, cols 0..63) chunk. alpha computed inline per edge
// (same value in all 16 lanes — no cross-lane ops anywhere). den accumulates
// identically per lane -> epilogue reciprocal needs no reduce. 4-deep main
// loop: 4 independent ssrc->elr->row chains, 12 VMEM in flight.
template<int H>
__global__ __launch_bounds__(256) void k_agg_gp(
    const unsigned short* __restrict__ fhb,  // [N][128] f16
    const float* __restrict__ elr,           // [N][4]
    const int* __restrict__ row_ptr, const int* __restrict__ ssrc,
    const float* __restrict__ bias, const float* __restrict__ res,
    int act, int res_from_fh,
    float* __restrict__ out, int out_ld, unsigned* __restrict__ outb, int N){
  const int t = threadIdx.x;
  const int gq = t >> 4, c = t & 15;         // group, lane-in-group
  const int n = blockIdx.x*16 + gq;
  if (n >= N) return;
  const int beg = row_ptr[n], end = row_ptr[n+1];
  const float er0 = elr[n*4+2];
  const float er1 = (H == 2) ? elr[n*4+3] : 0.f;

  const char* fhbB = (const char*)fhb;       // row = 256 B, 32-bit offsets
  const unsigned cb = (H == 2) ? ((unsigned)c << 4) : ((unsigned)c << 3);
  constexpr int PC = (H == 2) ? 8 : 4;       // cols per lane

  float acc[PC];
  #pragma unroll
  for (int k = 0; k < PC; k++) acc[k] = 0.f;
  float den0 = 0.f, den1 = 0.f;

  int i = beg;
  for (; i + 3 < end; i += 4){               // 4-deep: 4 independent chains
    int s0 = ssrc[i],   s1 = ssrc[i+1];
    int s2 = ssrc[i+2], s3 = ssrc[i+3];
    float2 el0 = *(const float2*)(elr + s0*4);
    float2 el1 = *(const float2*)(elr + s1*4);
    float2 el2 = *(const float2*)(elr + s2*4);
    float2 el3 = *(const float2*)(elr + s3*4);
    if (H == 2){
      uint4 w0 = *(const uint4*)(fhbB + (((unsigned)s0 << 8) + cb));
      uint4 w1 = *(const uint4*)(fhbB + (((unsigned)s1 << 8) + cb));
      uint4 w2 = *(const uint4*)(fhbB + (((unsigned)s2 << 8) + cb));
      uint4 w3 = *(const uint4*)(fhbB + (((unsigned)s3 << 8) + cb));
      float e00 = __expf(fminf(lrelu(el0.x + er0), 30.f));
      float e10 = __expf(fminf(lrelu(el1.x + er0), 30.f));
      float e20 = __expf(fminf(lrelu(el2.x + er0), 30.f));
      float e30 = __expf(fminf(lrelu(el3.x + er0), 30.f));
      float e01 = __expf(fminf(lrelu(el0.y + er1), 30.f));
      float e11 = __expf(fminf(lrelu(el1.y + er1), 30.f));
      float e21 = __expf(fminf(lrelu(el2.y + er1), 30.f));
      float e31 = __expf(fminf(lrelu(el3.y + er1), 30.f));
      den0 += (e00 + e10) + (e20 + e30);
      den1 += (e01 + e11) + (e21 + e31);
      float a0 = (c < 8) ? e00 : e01;        // head = col/64
      float a1 = (c < 8) ? e10 : e11;
      float a2 = (c < 8) ? e20 : e21;
      float a3 = (c < 8) ? e30 : e31;
      const __half2* h0 = (const __half2*)&w0;
      const __half2* h1 = (const __half2*)&w1;
      const __half2* h2 = (const __half2*)&w2;
      const __half2* h3 = (const __half2*)&w3;
      #pragma unroll
      for (int q = 0; q < 4; q++){
        acc[2*q]   = fmaf((float)h0[q].x, a0, acc[2*q]);
        acc[2*q+1] = fmaf((float)h0[q].y, a0, acc[2*q+1]);
        acc[2*q]   = fmaf((float)h1[q].x, a1, acc[2*q]);
        acc[2*q+1] = fmaf((float)h1[q].y, a1, acc[2*q+1]);
        acc[2*q]   = fmaf((float)h2[q].x, a2, acc[2*q]);
        acc[2*q+1] = fmaf((float)h2[q].y, a2, acc[2*q+1]);
        acc[2*q]   = fmaf((float)h3[q].x, a3, acc[2*q]);
        acc[2*q+1] = fmaf((float)h3[q].y, a3, acc[2*q+1]);
      }
    } else {
      uint2 w0 = *(const uint2*)(fhbB + (((unsigned)s0 << 8) + cb));
      uint2 w1 = *(const uint2*)(fhbB + (((unsigned)s1 << 8) + cb));
      uint2 w2 = *(const uint2*)(fhbB + (((unsigned)s2 << 8) + cb));
      uint2 w3 = *(const uint2*)(fhbB + (((unsigned)s3 << 8) + cb));
      float e00 = __expf(fminf(lrelu(el0.x + er0), 30.f));
      float e10 = __expf(fminf(lrelu(el1.x + er0), 30.f));
      float e20 = __expf(fminf(lrelu(el2.x + er0), 30.f));
      float e30 = __expf(fminf(lrelu(el3.x + er0), 30.f));
      den0 += (e00 + e10) + (e20 + e30);
      const __half2* h0 = (const __half2*)&w0;
      const __half2* h1 = (const __half2*)&w1;
      const __half2* h2 = (const __half2*)&w2;
      const __half2* h3 = (const __half2*)&w3;
      #pragma unroll
      for (int q = 0; q < 2; q++){
        acc[2*q]   = fmaf((float)h0[q].x, e00, acc[2*q]);
        acc[2*q+1] = fmaf((float)h0[q].y, e00, acc[2*q+1]);
        acc[2*q]   = fmaf((float)h1[q].x, e10, acc[2*q]);
        acc[2*q+1] = fmaf((float)h1[q].y, e10, acc[2*q+1]);
        acc[2*q]   = fmaf((float)h2[q].x, e20, acc[2*q]);
        acc[2*q+1] = fmaf((float)h2[q].y, e20, acc[2*q+1]);
        acc[2*q]   = fmaf((float)h3[q].x, e30, acc[2*q]);
        acc[2*q+1] = fmaf((float)h3[q].y, e30, acc[2*q+1]);
      }
    }
  }
  for (; i < end; i++){                      // tail: 0-3 edges
    int s0 = ssrc[i];
    float2 el0 = *(const float2*)(elr + s0*4);
    float e00 = __expf(fminf(lrelu(el0.x + er0), 30.f));
    float e01 = (H == 2) ? __expf(fminf(lrelu(el0.y + er1), 30.f)) : 0.f;
    den0 += e00; den1 += e01;
    if (H == 2){
      uint4 w0 = *(const uint4*)(fhbB + (((unsigned)s0 << 8) + cb));
      float a0 = (c < 8) ? e00 : e01;
      const __half2* h0 = (const __half2*)&w0;
      #pragma unroll
      for (int q = 0; q < 4; q++){
        acc[2*q]   = fmaf((float)h0[q].x, a0, acc[2*q]);
        acc[2*q+1] = fmaf((float)h0[q].y, a0, acc[2*q+1]);
      }
    } else {
      uint2 w0 = *(const uint2*)(fhbB + (((unsigned)s0 << 8) + cb));
      const __half2* h0 = (const __half2*)&w0;
      #pragma unroll
      for (int q = 0; q < 2; q++){
        acc[2*q]   = fmaf((float)h0[q].x, e00, acc[2*q]);
        acc[2*q+1] = fmaf((float)h0[q].y, e00, acc[2*q+1]);
      }
    }
  }

  // epilogue: den identical across the group's lanes — no reduce needed.
  float rd0 = den0 > 0.f ? 1.f/den0 : 0.f;
  float rd1 = (H == 2 && den1 > 0.f) ? 1.f/den1 : 0.f;

  if (H == 2){
    float rs = (c < 8) ? rd0 : rd1;
    float o[8];
    const float4* b4 = (const float4*)(bias + c*8);
    float4 ba = b4[0], bb = b4[1];
    o[0]=fmaf(acc[0],rs,ba.x); o[1]=fmaf(acc[1],rs,ba.y);
    o[2]=fmaf(acc[2],rs,ba.z); o[3]=fmaf(acc[3],rs,ba.w);
    o[4]=fmaf(acc[4],rs,bb.x); o[5]=fmaf(acc[5],rs,bb.y);
    o[6]=fmaf(acc[6],rs,bb.z); o[7]=fmaf(acc[7],rs,bb.w);
    if (res){
      const float4* r4 = (const float4*)(res + (size_t)n*128 + c*8);
      float4 ra = r4[0], rb = r4[1];
      o[0]+=ra.x; o[1]+=ra.y; o[2]+=ra.z; o[3]+=ra.w;
      o[4]+=rb.x; o[5]+=rb.y; o[6]+=rb.z; o[7]+=rb.w;
    }
    if (act){
      #pragma unroll
      for (int k = 0; k < 8; k++) o[k] = elu1(o[k]);
    }
    if (out){
      float4* o4 = (float4*)(out + (size_t)n*out_ld + c*8);
      o4[0] = make_float4(o[0], o[1], o[2], o[3]);
      o4[1] = make_float4(o[4], o[5], o[6], o[7]);
    }
    if (outb){
      uint4 ob;
      ob.x = (unsigned)f2bf(o[0]) | ((unsigned)f2bf(o[1]) << 16);
      ob.y = (unsigned)f2bf(o[2]) | ((unsigned)f2bf(o[3]) << 16);
      ob.z = (unsigned)f2bf(o[4]) | ((unsigned)f2bf(o[5]) << 16);
      ob.w = (unsigned)f2bf(o[6]) | ((unsigned)f2bf(o[7]) << 16);
      *(uint4*)(outb + (size_t)n*64 + c*4) = ob;
    }
  } else {
    float o[4];
    #pragma unroll
    for (int k = 0; k < 4; k++) o[k] = fmaf(acc[k], rd0, bias[c*4 + k]);
    if (res_from_fh){
      uint2 r = *(const uint2*)(fhbB + (size_t)n*256 + 128 + c*8);
      const __half2* rp = (const __half2*)&r;
      o[0] += (float)rp[0].x; o[1] += (float)rp[0].y;
      o[2] += (float)rp[1].x; o[3] += (float)rp[1].y;
    }
    if (act){
      #pragma unroll
      for (int k = 0; k < 4; k++) o[k] = elu1(o[k]);
    }
    *(float4*)(out + (size_t)n*out_ld + c*4) = make_float4(o[0], o[1], o[2], o[3]);
  }
}

extern "C" void kernel_launch(void* const* d_in, const int* in_sizes, int n_in,
                              void* d_out, int out_size, void* d_ws, size_t ws_size,
                              hipStream_t stream) {
  const int*   feat = (const int*)  d_in[0];
  const float* fv   = (const float*)d_in[1];
  const int*   src  = (const int*)  d_in[2];
  const int*   dst  = (const int*)  d_in[3];
  const float* emb  = (const float*)d_in[4];
  const float* W0   = (const float*)d_in[5];
  const float* al0  = (const float*)d_in[6];
  const float* ar0  = (const float*)d_in[7];
  const float* b0   = (const float*)d_in[8];
  const float* W1   = (const float*)d_in[9];
  const float* al1  = (const float*)d_in[10];
  const float* ar1  = (const float*)d_in[11];
  const float* b1   = (const float*)d_in[12];
  const float* W2   = (const float*)d_in[13];
  const float* al2  = (const float*)d_in[14];
  const float* ar2  = (const float*)d_in[15];
  const float* b2   = (const float*)d_in[16];
  const float* rW2  = (const float*)d_in[17];
  const int N = in_sizes[0] / 8;   // 50000
  const int E = in_sizes[2];       // 800000

  size_t off = 0;
  auto alloc = [&](size_t bytes) -> void* {
    void* p = (char*)d_ws + off;
    off = (off + bytes + 255) & ~(size_t)255;
    return p;
  };
  unsigned short* P1 = (unsigned short*)alloc((size_t)N*128*sizeof(unsigned short)); // fhb f16
  float* P2     = (float*)alloc((size_t)N*128*sizeof(float));                        // layer0 out (res for layer1)
  unsigned short* hb = (unsigned short*)alloc((size_t)N*128*sizeof(unsigned short)); // h bf16
  float* elr    = (float*)alloc((size_t)N*4*sizeof(float));
  int* row_ptr  = (int*)alloc((size_t)(N+1)*sizeof(int));
  int* counts   = (int*)alloc((size_t)N*sizeof(int));
  int* rank     = (int*)alloc((size_t)E*sizeof(int));
  int* ssrc     = (int*)alloc((size_t)E*sizeof(int));
  int* bsum     = (int*)alloc(256*sizeof(int));
  unsigned short* Wt0 = (unsigned short*)alloc((size_t)128*64*sizeof(unsigned short));
  unsigned short* Wt1 = (unsigned short*)alloc((size_t)128*128*sizeof(unsigned short));
  unsigned short* Wt2 = (unsigned short*)alloc((size_t)128*128*sizeof(unsigned short));

  int nb1 = (N + 255) / 256;
  int eb  = (E + 255) / 256;
  int gt  = (N + 63)/64;
  int ngp = (N + 15)/16;

  // setup: zero counts + weight preps (one launch)
  k_setup<<<(N + 128*64 + 2*128*128 + 255)/256, 256, 0, stream>>>(
      counts, N, W0, W1, W2, rW2, Wt0, Wt1, Wt2);
  // fused: layer-0 GEMM (EMBED) || edge histogram+rank (independent tasks)
  k_gemm0_hist<<<gt + eb, 256, 0, stream>>>(feat, fv, emb, Wt0, al0, ar0,
                                            P1, elr, N, gt,
                                            dst, counts, rank, E);
  // CSR finish: scans + atomic-free scatter
  k_scan_local<<<nb1, 256, 0, stream>>>(counts, row_ptr, bsum, N);
  k_scan_top<<<1, 256, 0, stream>>>(bsum, nb1);
  k_scan_fix<<<nb1, 256, 0, stream>>>(row_ptr, bsum, N);
  k_scatter2<<<eb, 256, 0, stream>>>(src, dst, rank, row_ptr, ssrc, E);

  // layer 0 aggregation: H=2, no residual, elu
  k_agg_gp<2><<<ngp, 256, 0, stream>>>(P1, elr, row_ptr, ssrc, b0, nullptr,
                                       1, 0, P2, 128, (unsigned*)hb, N);
  // layer 1: in=128, H=2, identity residual, elu; float out unused -> skip store
  k_gemm_mfma<128,2,false><<<gt, 256, 0, stream>>>(hb, nullptr, nullptr, nullptr,
                                                   Wt1, al1, ar1, P1, elr, N);
  k_agg_gp<2><<<ngp, 256, 0, stream>>>(P1, elr, row_ptr, ssrc, b1, P2,
                                       1, 0, nullptr, 128, (unsigned*)hb, N);
  // layer 2: in=128, H=1, projected residual (fh cols 64..127 = h@resW2), no act
  k_gemm_mfma<128,1,false><<<gt, 256, 0, stream>>>(hb, nullptr, nullptr, nullptr,
                                                   Wt2, al2, ar2, P1, elr, N);
  k_agg_gp<1><<<ngp, 256, 0, stream>>>(P1, elr, row_ptr, ssrc, b2, nullptr,
                                       0, 1, (float*)d_out, 64, nullptr, N);
}